// Round 11
// baseline (8066.024 us; speedup 1.0000x reference)
//
#include <hip/hip_runtime.h>
#include <stdint.h>

// LSTM B=256,T=512,F=32,U=350; gates i,f,g(relu),o; h=o*relu(c); out=h.dw+db
//
// R11: latency-HIDING via interleaved independent recurrences.
//  - R6..R10 measured: any serial cross-CU h exchange costs ~5.5us/step
//    (IF$ round trip + retry granularity + 22-producer convoy); sc0/XCD
//    schemes never validated. So stop shortening the latency — hide it.
//  - 11 col-blocks x 4 group-sets = 44 blocks. Block (j,s) owns cols
//    [32j,32j+32) x 4 gates (weights reg-resident, 192 VGPRs/lane) for the
//    4 batch groups of set s. Inner loop interleaves the 4 independent
//    recurrences: revisit period ~3 group-steps (~0.9us) > store flight
//    (~0.4us) => tags valid on arrival; exchange off the critical path.
//  - h exchange: R7/R9's proven tag-in-word protocol (u32 = bf16(h)<<16 |
//    step tag), agent-scope relaxed atomics only, ping-pong depth 2 per
//    group, per-wave validation, retry-forever. No fences, no sc0, no
//    placement assumptions, no claiming. Induction per group unchanged.
//  - Next group's 44 h-words prefetched into a second register buffer
//    during current group's MFMA/update; validation on consumption.
//  - x converted f32->bf16 in-kernel (prep_x dropped; ws ~13.3MB).
//  - Dense head: per-wave 16-col shfl reduce -> wpart[grp][tile][row][t];
//    reduce_out sums 22 tiles + bias.

#define T_    512
#define F_    32
#define U_    350
#define G4    1400
#define NGRP  16
#define NB    16
#define KC    12
#define NT    88
#define HROW  352
#define BG    4               // groups interleaved per block
#define NSET  (NGRP/BG)       // 4
#define NCOLB 11
#define NBLK  (NCOLB*NSET)    // 44

typedef __attribute__((ext_vector_type(8))) short  short8;
typedef __attribute__((ext_vector_type(4))) float  float4_;
typedef __attribute__((ext_vector_type(4))) uint32_t u32x4;
typedef unsigned long long u64t;

__device__ __forceinline__ short f2bf(float f) {
  union { float f; uint32_t u; } v; v.f = f;
  return (short)((v.u + 0x7FFFu + ((v.u >> 16) & 1u)) >> 16);
}

// ---- workspace layout (bytes) ----
#define SZ_W    (NT*KC*64*8*2u)                 // 1,081,344
#define OFF_HSA (SZ_W)
#define SZ_HSA  (NGRP*2u*NB*HROW*4u)            // 720,896
#define OFF_WP  (OFF_HSA + SZ_HSA)
#define SZ_WP   (NGRP*22u*NB*T_*4u)             // 11,534,336  (total ~13.3MB)

// ---- prep: W_swz[kc][tile][lane][8] bf16 in MFMA B-fragment order ----
__global__ void prep_w(const float* __restrict__ kern,
                       const float* __restrict__ rk,
                       const float* __restrict__ bias,
                       short* __restrict__ wswz) {
  const int tile = blockIdx.x, lane = threadIdx.x;
  const int g = tile / 22, jt = tile % 22;
  const int colg = jt * 16 + (lane & 15);
  const int src = g * U_ + colg;
  const bool valid = (colg < U_);
  const int kbase = (lane >> 4) * 8;
  for (int kc = 0; kc < KC; ++kc) {
    short8 pack;
    #pragma unroll
    for (int jj = 0; jj < 8; ++jj) {
      int k = kc * 32 + kbase + jj;
      float v = 0.f;
      if (valid) {
        if (k < F_)            v = kern[k * G4 + src];
        else if (k < F_ + U_)  v = rk[(k - F_) * G4 + src];
        else if (k == F_ + U_) v = bias[src];
      }
      pack[jj] = f2bf(v);
    }
    *(short8*)(wswz + (((size_t)kc * NT + tile) * 64 + lane) * 8) = pack;
  }
}

// ---- init: slot1 = h_{-1}=0 tag0 (+bf16 1.0 at bias col 350) ----
__global__ void init_all(uint32_t* __restrict__ hsa) {
  int i = blockIdx.x * 256 + threadIdx.x;        // 90112 threads
  int c = i % HROW;
  int grp = i / (NB * HROW), rem = i % (NB * HROW);
  hsa[(grp * 2 + 1) * NB * HROW + rem] = (c == 350) ? 0x3F800000u : 0u;
}

// ---- tagged h tile load (44 u64 agent loads -> 22 u32x4) ----
__device__ __forceinline__ void load_htile(u32x4* dst, const uint32_t* hq) {
  #pragma unroll
  for (int i = 0; i < 11; ++i) {
    const u64t* p = (const u64t*)(hq + i * 32);
    u64t q0 = __hip_atomic_load(p + 0, __ATOMIC_RELAXED, __HIP_MEMORY_SCOPE_AGENT);
    u64t q1 = __hip_atomic_load(p + 1, __ATOMIC_RELAXED, __HIP_MEMORY_SCOPE_AGENT);
    u64t q2 = __hip_atomic_load(p + 2, __ATOMIC_RELAXED, __HIP_MEMORY_SCOPE_AGENT);
    u64t q3 = __hip_atomic_load(p + 3, __ATOMIC_RELAXED, __HIP_MEMORY_SCOPE_AGENT);
    dst[2*i]   = (u32x4){(uint32_t)q0, (uint32_t)(q0>>32), (uint32_t)q1, (uint32_t)(q1>>32)};
    dst[2*i+1] = (u32x4){(uint32_t)q2, (uint32_t)(q2>>32), (uint32_t)q3, (uint32_t)(q3>>32)};
  }
}

__device__ __forceinline__ uint32_t tag_bad(const u32x4* q, uint32_t tag) {
  uint32_t bad = 0;
  #pragma unroll
  for (int i = 0; i < 22; ++i) {
    u32x4 xo = q[i] ^ tag;
    bad |= (xo[0] | xo[1] | xo[2] | xo[3]) & 0xFFFFu;
  }
  return bad;
}

// ---- main: 44 persistent blocks, 4 interleaved recurrences each ----
__global__ __launch_bounds__(128)
__attribute__((amdgpu_waves_per_eu(1, 1)))
void lstm_kernel(const float* __restrict__ x, const short* __restrict__ wswz,
                 uint32_t* __restrict__ hsa,
                 const float* __restrict__ dense_w, float* __restrict__ wpart) {
  const int tid  = threadIdx.x;
  const int lane = tid & 63;
  const int wv   = tid >> 6;            // 0..1
  const int l15  = lane & 15;
  const int quad = lane >> 4;
  const int j    = blockIdx.x % NCOLB;  // col-block 0..10
  const int s    = blockIdx.x / NCOLB;  // group-set 0..3
  const int tileg = 2 * j + wv;         // col tile 0..21

  // weights -> registers ONCE: 192 regs/lane
  short8 wreg[4][KC];
  #pragma unroll
  for (int g = 0; g < 4; ++g)
    #pragma unroll
    for (int kc = 0; kc < KC; ++kc)
      wreg[g][kc] = *(const short8*)(wswz +
          (((size_t)kc * NT + (g * 22 + tileg)) * 64 + lane) * 8);

  const int col = tileg * 16 + l15;                // gate-relative col 0..351
  const float dwv = (col < U_) ? dense_w[col] : 0.f;
  float cst[BG][4];
  #pragma unroll
  for (int gi = 0; gi < BG; ++gi)
    #pragma unroll
    for (int r = 0; r < 4; ++r) cst[gi][r] = 0.f;

  const int laneoff = l15 * HROW + quad * 8;       // words
  uint32_t* hgrp0 = hsa + (size_t)(s * BG) * 2 * NB * HROW;
  const float* xg0 = x + ((size_t)(s * BG * NB + l15) * T_) * F_ + quad * 8;

  u32x4 fq[2][22];
  // prologue: prefetch (t=0, gi=0) from slot 1
  load_htile(fq[0], hgrp0 + (size_t)1 * NB * HROW + laneoff);

  #pragma unroll 1
  for (int t = 0; t < T_; ++t) {
    const uint32_t tag  = (uint32_t)t;
    const uint32_t otag = (uint32_t)(t + 1);
    const size_t rdoff = ((size_t)((t + 1) & 1)) * NB * HROW;
    const size_t wroff = ((size_t)(t & 1)) * NB * HROW;

    #pragma unroll
    for (int gi = 0; gi < BG; ++gi) {
      const int cur = gi & 1, nxt = cur ^ 1;
      uint32_t* hb = hgrp0 + (size_t)gi * 2 * NB * HROW;

      // x A-frag: 8 f32 -> bf16 (k = quad*8..+8 of K-rows 0..31)
      const float* xp = xg0 + (size_t)gi * NB * T_ * F_ + (size_t)t * F_;
      float4_ xv0 = *(const float4_*)(xp);
      float4_ xv1 = *(const float4_*)(xp + 4);
      short8 axf;
      #pragma unroll
      for (int jj = 0; jj < 4; ++jj) { axf[jj] = f2bf(xv0[jj]); axf[4 + jj] = f2bf(xv1[jj]); }

      // kc=0 (x) MFMA
      float4_ acc[4];
      #pragma unroll
      for (int g = 0; g < 4; ++g) {
        float4_ z = (float4_){0.f, 0.f, 0.f, 0.f};
        acc[g] = __builtin_amdgcn_mfma_f32_16x16x32_bf16(axf, wreg[g][0], z, 0, 0, 0);
      }

      // validate prefetched h tile (retry-reload if stale; rare in steady state)
      {
        bool ok = (bool)__all((int)(tag_bad(fq[cur], tag) == 0));
        while (!ok) {
          load_htile(fq[cur], (const uint32_t*)hb + rdoff + laneoff);
          ok = (bool)__all((int)(tag_bad(fq[cur], tag) == 0));
        }
      }

      // prefetch next group-step's h tile (flies during MFMA/update)
      if (t < T_ - 1 || gi < BG - 1) {
        const uint32_t* hqn = (gi < BG - 1)
            ? hgrp0 + (size_t)(gi + 1) * 2 * NB * HROW + rdoff + laneoff
            : hgrp0 + wroff + laneoff;   // (gi=0, t+1): parity (t+2)&1 == t&1
        load_htile(fq[nxt], hqn);
      }

      // repack hi16 pairs -> bf16 A-frags; MFMA kc=1..11
      #pragma unroll
      for (int i = 0; i < 11; ++i) {
        union { uint32_t w[4]; short8 sh; } u;
        #pragma unroll
        for (int k = 0; k < 4; ++k) {
          uint32_t lo = fq[cur][2*i + (k >> 1)][(k & 1) * 2];
          uint32_t hi = fq[cur][2*i + (k >> 1)][(k & 1) * 2 + 1];
          u.w[k] = (lo >> 16) | (hi & 0xFFFF0000u);
        }
        #pragma unroll
        for (int g = 0; g < 4; ++g)
          acc[g] = __builtin_amdgcn_mfma_f32_16x16x32_bf16(u.sh, wreg[g][i + 1], acc[g], 0, 0, 0);
      }

      // gate update (lane: rows quad*4+r at its col) + tagged publish
      float hn[4];
      #pragma unroll
      for (int r = 0; r < 4; ++r) {
        float ig = __builtin_amdgcn_rcpf(1.f + __expf(-acc[0][r]));
        float fg = __builtin_amdgcn_rcpf(1.f + __expf(-acc[1][r]));
        float gg = fmaxf(acc[2][r], 0.f);
        float og = __builtin_amdgcn_rcpf(1.f + __expf(-acc[3][r]));
        float cn = fg * cst[gi][r] + ig * gg;
        cst[gi][r] = cn;
        hn[r] = og * fmaxf(cn, 0.f);
        short hs = f2bf(hn[r]);
        if (col == 350) hs = (short)0x3F80;      // bias-row input stays 1.0
        else if (col == 351) hs = 0;
        uint32_t word = ((uint32_t)(unsigned short)hs << 16) | otag;
        __hip_atomic_store(hb + wroff + (size_t)(quad * 4 + r) * HROW + col, word,
                           __ATOMIC_RELAXED, __HIP_MEMORY_SCOPE_AGENT);
      }

      // dense head partial: reduce over this wave's 16 cols -> wpart
      #pragma unroll
      for (int r = 0; r < 4; ++r) {
        float sv = hn[r] * dwv;
        sv += __shfl_xor(sv, 1); sv += __shfl_xor(sv, 2);
        sv += __shfl_xor(sv, 4); sv += __shfl_xor(sv, 8);
        if (l15 == 0)
          wpart[(((size_t)(s * BG + gi) * 22 + tileg) * NB + quad * 4 + r) * T_ + t] = sv;
      }
    }
  }
}

// ---- final: out[b,t] = db + sum_{tile} wpart[grp][tile][row][t] ----
__global__ void reduce_out(const float* __restrict__ wpart,
                           const float* __restrict__ dense_b,
                           float* __restrict__ out) {
  int i = blockIdx.x * 256 + threadIdx.x;   // i = b*T + t
  int b = i >> 9, t = i & 511;
  int grp = b >> 4, row = b & 15;
  float sv = dense_b[0];
  #pragma unroll
  for (int tile = 0; tile < 22; ++tile)
    sv += wpart[(((size_t)grp * 22 + tile) * NB + row) * T_ + t];
  out[i] = sv;
}

extern "C" void kernel_launch(void* const* d_in, const int* in_sizes, int n_in,
                              void* d_out, int out_size, void* d_ws, size_t ws_size,
                              hipStream_t stream) {
  const float* x    = (const float*)d_in[0];
  const float* kern = (const float*)d_in[1];
  const float* rk   = (const float*)d_in[2];
  const float* bias = (const float*)d_in[3];
  const float* dw   = (const float*)d_in[4];
  const float* db   = (const float*)d_in[5];
  float* out = (float*)d_out;

  char* ws = (char*)d_ws;
  short*    wswz  = (short*)(ws);
  uint32_t* hsa   = (uint32_t*)(ws + OFF_HSA);
  float*    wpart = (float*)(ws + OFF_WP);

  prep_w<<<NT, 64, 0, stream>>>(kern, rk, bias, wswz);
  init_all<<<(NGRP * NB * HROW) / 256, 256, 0, stream>>>(hsa);
  lstm_kernel<<<NBLK, 128, 0, stream>>>(x, wswz, hsa, dw, wpart);
  reduce_out<<<(256 * T_) / 256, 256, 0, stream>>>(wpart, db, out);
}

// Round 12
// 7533.232 us; speedup vs baseline: 1.0707x; 1.0707x over previous
//
#include <hip/hip_runtime.h>
#include <stdint.h>

// LSTM B=256,T=512,F=32,U=350; gates i,f,g(relu),o; h=o*relu(c); out=h.dw+db
//
// R12: R11's interleaved-recurrence latency hiding, register-budget fixed.
//  - R11 post-mortem: fq[2][22] double-buffer (176 VGPRs) + 192 weight regs
//    overflowed the unified file -> scratch spills (VGPR=256 cap, FETCH
//    790MB) -> 3.9us/group-step. Fix: single tagged prefetch buffer pf[22]
//    (88 regs) + repacked ready buffer rdy[11] (44 regs). Per slot:
//    validate pf -> repack to rdy (pf dead) -> issue next prefetch into pf
//    -> MFMA from rdy. ~220 arch VGPRs + 192 weights: fits, no spills.
//  - 11 col-blocks x 4 group-sets = 44 blocks (128 thr); block interleaves
//    4 independent batch-group recurrences; tile consumed at slot (t,gi)
//    was published at (t-1,gi) = 4 slots earlier; prefetch 1 slot ahead =>
//    3-slot slack >> fabric flight => exchange off the critical path.
//  - Exchange: R7/R9/R11 tag-in-word protocol (u32 = bf16(h)<<16 | tag),
//    agent-scope relaxed atomics, depth-2 ping-pong per group, per-wave
//    validation, retry-forever with s_sleep backoff. No fences/sc0/claims.
//  - repack via v_perm_b32 (1 op/word); x f32->bf16 in-kernel; dense head
//    partials straight to wpart; reduce_out sums 22 tiles + bias.

#define T_    512
#define F_    32
#define U_    350
#define G4    1400
#define NGRP  16
#define NB    16
#define KC    12
#define NT    88
#define HROW  352
#define BG    4               // groups interleaved per block
#define NSET  (NGRP/BG)       // 4
#define NCOLB 11
#define NBLK  (NCOLB*NSET)    // 44

typedef __attribute__((ext_vector_type(8))) short  short8;
typedef __attribute__((ext_vector_type(4))) float  float4_;
typedef __attribute__((ext_vector_type(4))) uint32_t u32x4;
typedef unsigned long long u64t;

__device__ __forceinline__ short f2bf(float f) {
  union { float f; uint32_t u; } v; v.f = f;
  return (short)((v.u + 0x7FFFu + ((v.u >> 16) & 1u)) >> 16);
}

// ---- workspace layout (bytes) ----
#define SZ_W    (NT*KC*64*8*2u)                 // 1,081,344
#define OFF_HSA (SZ_W)
#define SZ_HSA  (NGRP*2u*NB*HROW*4u)            // 720,896
#define OFF_WP  (OFF_HSA + SZ_HSA)
#define SZ_WP   (NGRP*22u*NB*T_*4u)             // 11,534,336

// ---- prep: W_swz[kc][tile][lane][8] bf16 in MFMA B-fragment order ----
__global__ void prep_w(const float* __restrict__ kern,
                       const float* __restrict__ rk,
                       const float* __restrict__ bias,
                       short* __restrict__ wswz) {
  const int tile = blockIdx.x, lane = threadIdx.x;
  const int g = tile / 22, jt = tile % 22;
  const int colg = jt * 16 + (lane & 15);
  const int src = g * U_ + colg;
  const bool valid = (colg < U_);
  const int kbase = (lane >> 4) * 8;
  for (int kc = 0; kc < KC; ++kc) {
    short8 pack;
    #pragma unroll
    for (int jj = 0; jj < 8; ++jj) {
      int k = kc * 32 + kbase + jj;
      float v = 0.f;
      if (valid) {
        if (k < F_)            v = kern[k * G4 + src];
        else if (k < F_ + U_)  v = rk[(k - F_) * G4 + src];
        else if (k == F_ + U_) v = bias[src];
      }
      pack[jj] = f2bf(v);
    }
    *(short8*)(wswz + (((size_t)kc * NT + tile) * 64 + lane) * 8) = pack;
  }
}

// ---- init: slot1 = h_{-1}=0 tag0 (+bf16 1.0 at bias col 350) ----
__global__ void init_all(uint32_t* __restrict__ hsa) {
  int i = blockIdx.x * 256 + threadIdx.x;        // 90112 threads
  int c = i % HROW;
  int grp = i / (NB * HROW), rem = i % (NB * HROW);
  hsa[(grp * 2 + 1) * NB * HROW + rem] = (c == 350) ? 0x3F800000u : 0u;
}

// ---- tagged h tile load (44 u64 agent loads -> 22 u32x4) ----
__device__ __forceinline__ void load_htile(u32x4* dst, const uint32_t* hq) {
  #pragma unroll
  for (int i = 0; i < 11; ++i) {
    const u64t* p = (const u64t*)(hq + i * 32);
    u64t q0 = __hip_atomic_load(p + 0, __ATOMIC_RELAXED, __HIP_MEMORY_SCOPE_AGENT);
    u64t q1 = __hip_atomic_load(p + 1, __ATOMIC_RELAXED, __HIP_MEMORY_SCOPE_AGENT);
    u64t q2 = __hip_atomic_load(p + 2, __ATOMIC_RELAXED, __HIP_MEMORY_SCOPE_AGENT);
    u64t q3 = __hip_atomic_load(p + 3, __ATOMIC_RELAXED, __HIP_MEMORY_SCOPE_AGENT);
    dst[2*i]   = (u32x4){(uint32_t)q0, (uint32_t)(q0>>32), (uint32_t)q1, (uint32_t)(q1>>32)};
    dst[2*i+1] = (u32x4){(uint32_t)q2, (uint32_t)(q2>>32), (uint32_t)q3, (uint32_t)(q3>>32)};
  }
}

__device__ __forceinline__ uint32_t tag_bad(const u32x4* q, uint32_t tag) {
  uint32_t bad = 0;
  #pragma unroll
  for (int i = 0; i < 22; ++i) {
    u32x4 xo = q[i] ^ tag;
    bad |= (xo[0] | xo[1] | xo[2] | xo[3]) & 0xFFFFu;
  }
  return bad;
}

// ---- main: 44 persistent blocks, 4 interleaved recurrences each ----
__global__ __launch_bounds__(128)
__attribute__((amdgpu_waves_per_eu(1, 1)))
void lstm_kernel(const float* __restrict__ x, const short* __restrict__ wswz,
                 uint32_t* __restrict__ hsa,
                 const float* __restrict__ dense_w, float* __restrict__ wpart) {
  const int tid  = threadIdx.x;
  const int lane = tid & 63;
  const int wv   = tid >> 6;            // 0..1
  const int l15  = lane & 15;
  const int quad = lane >> 4;
  const int j    = blockIdx.x % NCOLB;  // col-block 0..10
  const int s    = blockIdx.x / NCOLB;  // group-set 0..3
  const int tileg = 2 * j + wv;         // col tile 0..21

  // weights -> registers ONCE: 192 regs/lane (unified VGPR/AGPR file)
  short8 wreg[4][KC];
  #pragma unroll
  for (int g = 0; g < 4; ++g)
    #pragma unroll
    for (int kc = 0; kc < KC; ++kc)
      wreg[g][kc] = *(const short8*)(wswz +
          (((size_t)kc * NT + (g * 22 + tileg)) * 64 + lane) * 8);

  const int col = tileg * 16 + l15;                // gate-relative col 0..351
  const float dwv = (col < U_) ? dense_w[col] : 0.f;
  float cst[BG][4];
  #pragma unroll
  for (int gi = 0; gi < BG; ++gi)
    #pragma unroll
    for (int r = 0; r < 4; ++r) cst[gi][r] = 0.f;

  const int laneoff = l15 * HROW + quad * 8;       // words
  uint32_t* hgrp0 = hsa + (size_t)(s * BG) * 2 * NB * HROW;
  const float* xg0 = x + ((size_t)(s * BG * NB + l15) * T_) * F_ + quad * 8;

  u32x4 pf[22];        // tagged prefetch buffer (88 VGPRs)
  // prologue: prefetch slot (t=0, gi=0): group 0, tag 0, parity 1
  load_htile(pf, hgrp0 + (size_t)1 * NB * HROW + laneoff);

  #pragma unroll 1
  for (int t = 0; t < T_; ++t) {
    const uint32_t tag  = (uint32_t)t;
    const uint32_t otag = (uint32_t)(t + 1);
    const size_t rdoff = ((size_t)((t + 1) & 1)) * NB * HROW;
    const size_t wroff = ((size_t)(t & 1)) * NB * HROW;

    #pragma unroll
    for (int gi = 0; gi < BG; ++gi) {
      uint32_t* hb = hgrp0 + (size_t)gi * 2 * NB * HROW;

      // x A-frag source (f32; converted below)
      const float* xp = xg0 + (size_t)gi * NB * T_ * F_ + (size_t)t * F_;
      float4_ xv0 = *(const float4_*)(xp);
      float4_ xv1 = *(const float4_*)(xp + 4);

      // validate prefetched tile for (t, gi); retry rare in steady state
      {
        bool ok = (bool)__all((int)(tag_bad(pf, tag) == 0));
        while (!ok) {
          __builtin_amdgcn_s_sleep(2);
          load_htile(pf, (const uint32_t*)hb + rdoff + laneoff);
          ok = (bool)__all((int)(tag_bad(pf, tag) == 0));
        }
      }

      // repack pf -> rdy (v_perm: [lo_b2,lo_b3,hi_b2,hi_b3]); pf then dead
      short8 rdy[11];
      #pragma unroll
      for (int i = 0; i < 11; ++i) {
        union { uint32_t w[4]; short8 sh; } u;
        #pragma unroll
        for (int k = 0; k < 4; ++k) {
          uint32_t lo = pf[2*i + (k >> 1)][(k & 1) * 2];
          uint32_t hi = pf[2*i + (k >> 1)][(k & 1) * 2 + 1];
          u.w[k] = __builtin_amdgcn_perm(hi, lo, 0x07060302u);
        }
        rdy[i] = u.sh;
      }

      // issue prefetch for the NEXT slot (flies during MFMA/update)
      {
        const uint32_t* hqn = (gi < BG - 1)
            ? hgrp0 + (size_t)(gi + 1) * 2 * NB * HROW + rdoff + laneoff
            : hgrp0 + wroff + laneoff;   // (t+1, gi=0): parity (t+2)&1 == t&1
        load_htile(pf, hqn);
      }

      // MFMA: kc=0 from x, kc=1..11 from rdy
      short8 axf;
      #pragma unroll
      for (int jj = 0; jj < 4; ++jj) { axf[jj] = f2bf(xv0[jj]); axf[4 + jj] = f2bf(xv1[jj]); }
      float4_ acc[4];
      #pragma unroll
      for (int g = 0; g < 4; ++g) {
        float4_ z = (float4_){0.f, 0.f, 0.f, 0.f};
        acc[g] = __builtin_amdgcn_mfma_f32_16x16x32_bf16(axf, wreg[g][0], z, 0, 0, 0);
      }
      #pragma unroll
      for (int i = 0; i < 11; ++i)
        #pragma unroll
        for (int g = 0; g < 4; ++g)
          acc[g] = __builtin_amdgcn_mfma_f32_16x16x32_bf16(rdy[i], wreg[g][i + 1], acc[g], 0, 0, 0);

      // gate update (lane: rows quad*4+r at its col) + tagged publish
      float hn[4];
      #pragma unroll
      for (int r = 0; r < 4; ++r) {
        float ig = __builtin_amdgcn_rcpf(1.f + __expf(-acc[0][r]));
        float fg = __builtin_amdgcn_rcpf(1.f + __expf(-acc[1][r]));
        float gg = fmaxf(acc[2][r], 0.f);
        float og = __builtin_amdgcn_rcpf(1.f + __expf(-acc[3][r]));
        float cn = fg * cst[gi][r] + ig * gg;
        cst[gi][r] = cn;
        hn[r] = og * fmaxf(cn, 0.f);
        short hs = f2bf(hn[r]);
        if (col == 350) hs = (short)0x3F80;      // bias-row input stays 1.0
        else if (col == 351) hs = 0;
        uint32_t word = ((uint32_t)(unsigned short)hs << 16) | otag;
        __hip_atomic_store(hb + wroff + (size_t)(quad * 4 + r) * HROW + col, word,
                           __ATOMIC_RELAXED, __HIP_MEMORY_SCOPE_AGENT);
      }

      // dense head partial: reduce over this wave's 16 cols -> wpart
      #pragma unroll
      for (int r = 0; r < 4; ++r) {
        float sv = hn[r] * dwv;
        sv += __shfl_xor(sv, 1); sv += __shfl_xor(sv, 2);
        sv += __shfl_xor(sv, 4); sv += __shfl_xor(sv, 8);
        if (l15 == 0)
          wpart[(((size_t)(s * BG + gi) * 22 + tileg) * NB + quad * 4 + r) * T_ + t] = sv;
      }
    }
  }
}

// ---- final: out[b,t] = db + sum_{tile} wpart[grp][tile][row][t] ----
__global__ void reduce_out(const float* __restrict__ wpart,
                           const float* __restrict__ dense_b,
                           float* __restrict__ out) {
  int i = blockIdx.x * 256 + threadIdx.x;   // i = b*T + t
  int b = i >> 9, t = i & 511;
  int grp = b >> 4, row = b & 15;
  float sv = dense_b[0];
  #pragma unroll
  for (int tile = 0; tile < 22; ++tile)
    sv += wpart[(((size_t)grp * 22 + tile) * NB + row) * T_ + t];
  out[i] = sv;
}

extern "C" void kernel_launch(void* const* d_in, const int* in_sizes, int n_in,
                              void* d_out, int out_size, void* d_ws, size_t ws_size,
                              hipStream_t stream) {
  const float* x    = (const float*)d_in[0];
  const float* kern = (const float*)d_in[1];
  const float* rk   = (const float*)d_in[2];
  const float* bias = (const float*)d_in[3];
  const float* dw   = (const float*)d_in[4];
  const float* db   = (const float*)d_in[5];
  float* out = (float*)d_out;

  char* ws = (char*)d_ws;
  short*    wswz  = (short*)(ws);
  uint32_t* hsa   = (uint32_t*)(ws + OFF_HSA);
  float*    wpart = (float*)(ws + OFF_WP);

  prep_w<<<NT, 64, 0, stream>>>(kern, rk, bias, wswz);
  init_all<<<(NGRP * NB * HROW) / 256, 256, 0, stream>>>(hsa);
  lstm_kernel<<<NBLK, 128, 0, stream>>>(x, wswz, hsa, dw, wpart);
  reduce_out<<<(256 * T_) / 256, 256, 0, stream>>>(wpart, db, out);
}